// Round 5
// baseline (301.070 us; speedup 1.0000x reference)
//
#include <hip/hip_runtime.h>

#define DD 128

typedef __attribute__((ext_vector_type(8))) short bf16x8;
typedef __attribute__((ext_vector_type(4))) float f32x4;

__device__ inline unsigned short f2b(float f) {
    unsigned int u = __float_as_uint(f);
    u += 0x7fffu + ((u >> 16) & 1u);   // RNE
    return (unsigned short)(u >> 16);
}

// accumulate 8 bf16 (packed in uint4) into two float4
__device__ inline void bacc16(float4& a, float4& b, uint4 v) {
    a.x += __uint_as_float(v.x << 16);
    a.y += __uint_as_float(v.x & 0xffff0000u);
    a.z += __uint_as_float(v.y << 16);
    a.w += __uint_as_float(v.y & 0xffff0000u);
    b.x += __uint_as_float(v.z << 16);
    b.y += __uint_as_float(v.z & 0xffff0000u);
    b.z += __uint_as_float(v.w << 16);
    b.w += __uint_as_float(v.w & 0xffff0000u);
}

// ---- blocks 0..63: W [k][c] fp32 -> Wt [c][k] bf16; rest: deg[dst]++ ----
__global__ __launch_bounds__(256) void k_pre(const float* __restrict__ W,
                                             unsigned short* __restrict__ Wt,
                                             const int* __restrict__ dst, int E,
                                             int* __restrict__ deg) {
    const int bid = blockIdx.x;
    if (bid < 64) {
        int idx = bid * 256 + threadIdx.x;
        int k = idx >> 7, c = idx & 127;
        Wt[c * DD + k] = f2b(W[k * DD + c]);
    } else {
        const int nb = gridDim.x - 64;
        for (int e = (bid - 64) * 256 + threadIdx.x; e < E; e += nb * 256)
            atomicAdd(&deg[dst[e]], 1);
    }
}

// ---- CSR range allocation: per-wave exclusive scan of deg + one global
// atomic per wave (ranges contiguous, node order irrelevant). Also dinv. ----
__global__ __launch_bounds__(256) void k_scan(const int* __restrict__ deg,
                                              int* __restrict__ off,
                                              int* __restrict__ cur,
                                              float* __restrict__ dinv,
                                              int* __restrict__ gtot, int n) {
    const int d = blockIdx.x * 256 + threadIdx.x;
    const int lane = threadIdx.x & 63;
    int orig = (d < n) ? deg[d] : 0;
    int v = orig;
    #pragma unroll
    for (int m = 1; m < 64; m <<= 1) {
        int up = __shfl_up(v, m);
        if (lane >= m) v += up;
    }
    int base = 0;
    if (lane == 63) base = atomicAdd(gtot, v);
    base = __shfl(base, 63);
    int excl = base + v - orig;
    if (d < n) {
        off[d]  = excl;
        cur[d]  = excl;
        dinv[d] = rsqrtf((float)orig + 1.0f);
    }
}

// ---- FUSED: gemm role (blocks 0..ngemm-1) + CSR scatter role (rest) ----
// gemm: hs[r][c] = bf16( (x[r,:] @ W[:,c]) * dinv[r] )  (R1-verbatim body).
// scatter: csr[atomicAdd(cur[dst])] = src  (atomic-latency-bound; backfills
// the BW/MFMA-bound gemm blocks on the same CUs).
__global__ __launch_bounds__(256) void k_work(const float* __restrict__ x,
                                              const unsigned short* __restrict__ Wt,
                                              const float* __restrict__ dinv,
                                              unsigned short* __restrict__ hs,
                                              const int* __restrict__ src,
                                              const int* __restrict__ dst, int E,
                                              int* __restrict__ cur,
                                              int* __restrict__ csr,
                                              int n, int ngemm) {
    const int t = threadIdx.x;
    if ((int)blockIdx.x >= ngemm) {
        const int nb = gridDim.x - ngemm;
        for (int e = (blockIdx.x - ngemm) * 256 + t; e < E; e += nb * 256) {
            int dd = dst[e];
            int p = atomicAdd(&cur[dd], 1);
            csr[p] = src[e];
        }
        return;
    }

    const int wave = t >> 6, lane = t & 63;
    const int rowbase = blockIdx.x * 256 + wave * 64;
    const int l15 = lane & 15, l4 = lane >> 4;

    bf16x8 a[4][4];
    #pragma unroll
    for (int rb = 0; rb < 4; ++rb) {
        int r = rowbase + rb * 16 + l15;
        int rc = min(r, n - 1);
        const float* xr = x + (size_t)rc * DD;
        #pragma unroll
        for (int kc = 0; kc < 4; ++kc) {
            int k0 = kc * 32 + l4 * 8;
            float4 f0 = *(const float4*)(xr + k0);
            float4 f1 = *(const float4*)(xr + k0 + 4);
            bf16x8 fr;
            fr[0] = (short)f2b(f0.x); fr[1] = (short)f2b(f0.y);
            fr[2] = (short)f2b(f0.z); fr[3] = (short)f2b(f0.w);
            fr[4] = (short)f2b(f1.x); fr[5] = (short)f2b(f1.y);
            fr[6] = (short)f2b(f1.z); fr[7] = (short)f2b(f1.w);
            a[rb][kc] = fr;
        }
    }

    float dv[4][4];
    #pragma unroll
    for (int rb = 0; rb < 4; ++rb)
        #pragma unroll
        for (int vv = 0; vv < 4; ++vv) {
            int r = rowbase + rb * 16 + l4 * 4 + vv;
            dv[rb][vv] = dinv[min(r, n - 1)];
        }

    #pragma unroll
    for (int cb = 0; cb < 8; ++cb) {
        int c0 = cb * 16;
        f32x4 acc[4] = {};
        #pragma unroll
        for (int kc = 0; kc < 4; ++kc) {
            bf16x8 bfrag = *(const bf16x8*)(Wt + (size_t)(c0 + l15) * DD + kc * 32 + l4 * 8);
            #pragma unroll
            for (int rb = 0; rb < 4; ++rb)
                acc[rb] = __builtin_amdgcn_mfma_f32_16x16x32_bf16(a[rb][kc], bfrag, acc[rb], 0, 0, 0);
        }
        #pragma unroll
        for (int rb = 0; rb < 4; ++rb) {
            int r0 = rowbase + rb * 16 + l4 * 4;
            #pragma unroll
            for (int vv = 0; vv < 4; ++vv) {
                int r = r0 + vv;
                if (r < n)
                    hs[(size_t)r * DD + c0 + l15] = f2b(acc[rb][vv] * dv[rb][vv]);
            }
        }
    }
}

// ---- out[d] = (hs[d] + sum_{s in N(d)} hs[s]) * dinv[d] + b
// R1-verbatim (best measured: 64.2 us, ~3.8 TB/s random-gather wall).
__global__ __launch_bounds__(256, 8) void k_agg(const uint4* __restrict__ hsr,  // hs, row = 16 uint4
                                                const int* __restrict__ ssrc,
                                                const int* __restrict__ off,
                                                const int* __restrict__ cnt,
                                                const float* __restrict__ dinv,
                                                const float* __restrict__ bias,
                                                float* __restrict__ out, int n) {
    const int t = threadIdx.x;
    const int wave = t >> 6, lane = t & 63;
    const int q  = lane >> 4;      // quarter id 0..3
    const int ql = lane & 15;      // lane within quarter; covers bf16 cols [ql*8, ql*8+8)
    const int d = blockIdx.x * 4 + wave;
    if (d >= n) return;

    const int s0 = off[d];
    const int c  = cnt[d];

    float4 accA = {0.f, 0.f, 0.f, 0.f};
    float4 accB = {0.f, 0.f, 0.f, 0.f};

    // self row (independent, issues immediately)
    uint4 vself = hsr[(size_t)d * 16 + ql];

    // batch idx loads: 6 independent broadcast loads (quarter q, round r -> edge r*4+q)
    int idx[6];
    #pragma unroll
    for (int r = 0; r < 6; ++r) {
        int e = r * 4 + q;
        idx[r] = ssrc[s0 + ((e < c) ? e : 0)];   // in-bounds addr even when inactive
    }
    #pragma unroll
    for (int r = 0; r < 6; ++r) {
        int e = r * 4 + q;
        idx[r] = (e < c) ? idx[r] : d;           // inactive slots gather own row (safe)
    }

    // batch gathers: 6 independent 256B row reads in flight simultaneously
    uint4 val[6];
    #pragma unroll
    for (int r = 0; r < 6; ++r)
        val[r] = hsr[(size_t)idx[r] * 16 + ql];

    if (q == 0) bacc16(accA, accB, vself);
    #pragma unroll
    for (int r = 0; r < 6; ++r) {
        int e = r * 4 + q;
        if (e < c) bacc16(accA, accB, val[r]);
    }

    // rare tail: c > 24 (P ~ 2% at mean degree 16)
    for (int i = 24 + q; i < c; i += 4) {
        int s = ssrc[s0 + i];
        uint4 v = hsr[(size_t)s * 16 + ql];
        bacc16(accA, accB, v);
    }

    // fold the 4 quarters (bits 4 and 5 of lane id)
    #pragma unroll
    for (int m = 16; m <= 32; m <<= 1) {
        accA.x += __shfl_xor(accA.x, m);
        accA.y += __shfl_xor(accA.y, m);
        accA.z += __shfl_xor(accA.z, m);
        accA.w += __shfl_xor(accA.w, m);
        accB.x += __shfl_xor(accB.x, m);
        accB.y += __shfl_xor(accB.y, m);
        accB.z += __shfl_xor(accB.z, m);
        accB.w += __shfl_xor(accB.w, m);
    }

    if (q == 0) {
        float di = dinv[d];
        float4 b0 = ((const float4*)bias)[ql * 2];
        float4 b1 = ((const float4*)bias)[ql * 2 + 1];
        float4 o0, o1;
        o0.x = accA.x * di + b0.x;
        o0.y = accA.y * di + b0.y;
        o0.z = accA.z * di + b0.z;
        o0.w = accA.w * di + b0.w;
        o1.x = accB.x * di + b1.x;
        o1.y = accB.y * di + b1.y;
        o1.z = accB.z * di + b1.z;
        o1.w = accB.w * di + b1.w;
        float4* orow = (float4*)(out + (size_t)d * DD);
        orow[ql * 2]     = o0;
        orow[ql * 2 + 1] = o1;
    }
}

extern "C" void kernel_launch(void* const* d_in, const int* in_sizes, int n_in,
                              void* d_out, int out_size, void* d_ws, size_t ws_size,
                              hipStream_t stream) {
    const float* x  = (const float*)d_in[0];
    const int*   ei = (const int*)d_in[1];
    const float* W  = (const float*)d_in[2];
    const float* b  = (const float*)d_in[3];
    float* out = (float*)d_out;

    const int n = in_sizes[0] / DD;      // 100000
    const int E = in_sizes[1] / 2;       // 1600000
    const int* src = ei;
    const int* dst = ei + E;

    unsigned short* hs = (unsigned short*)d_ws;              // n*128 bf16 (25.6 MB)
    unsigned short* Wt = hs + (size_t)n * DD;                // 16384 bf16
    int*   csr  = (int*)(Wt + DD * DD);                      // E ints (6.4 MB)
    int*   off  = csr + E;                                   // n ints
    int*   cur  = off + n;                                   // n ints
    int*   deg  = cur + n;                                   // n ints
    int*   gtot = deg + n;                                   // 1 int (zeroed with deg)
    float* dinv = (float*)(gtot + 1);                        // n floats

    hipMemsetAsync(deg, 0, (size_t)(n + 1) * sizeof(int), stream);

    const int ngemm = (n + 255) / 256;                       // 391

    k_pre <<<64 + 1024, 256, 0, stream>>>(W, Wt, dst, E, deg);
    k_scan<<<(n + 255) / 256, 256, 0, stream>>>(deg, off, cur, dinv, gtot, n);
    k_work<<<ngemm + 1024, 256, 0, stream>>>(x, Wt, dinv, hs, src, dst, E,
                                             cur, csr, n, ngemm);
    k_agg <<<(n + 3) / 4, 256, 0, stream>>>((const uint4*)hs, csr, off, deg,
                                            dinv, b, out, n);
}

// Round 6
// 134.274 us; speedup vs baseline: 2.2422x; 2.2422x over previous
//
#include <hip/hip_runtime.h>

#define DD 128
#define CAP 12288          // per-bucket slot capacity (mean 8163, +45 sigma)

typedef __attribute__((ext_vector_type(8))) short bf16x8;
typedef __attribute__((ext_vector_type(4))) float f32x4;

__device__ inline unsigned short f2b(float f) {
    unsigned int u = __float_as_uint(f);
    u += 0x7fffu + ((u >> 16) & 1u);   // RNE
    return (unsigned short)(u >> 16);
}

// acc += bf16x8(v) * s
__device__ inline void bacc16f(float4& a, float4& b, uint4 v, float s) {
    a.x += __uint_as_float(v.x << 16) * s;
    a.y += __uint_as_float(v.x & 0xffff0000u) * s;
    a.z += __uint_as_float(v.y << 16) * s;
    a.w += __uint_as_float(v.y & 0xffff0000u) * s;
    b.x += __uint_as_float(v.z << 16) * s;
    b.y += __uint_as_float(v.z & 0xffff0000u) * s;
    b.z += __uint_as_float(v.w << 16) * s;
    b.w += __uint_as_float(v.w & 0xffff0000u) * s;
}

// ---- merged: W transpose->bf16 (blocks 0..63) + cursor init (block 64+) ----
__global__ __launch_bounds__(256) void k_pre(const float* __restrict__ W,
                                             unsigned short* __restrict__ Wt,
                                             int* __restrict__ cur, int nbuck) {
    int bid = blockIdx.x;
    if (bid < 64) {
        int idx = bid * 256 + threadIdx.x;
        int k = idx >> 7, c = idx & 127;
        Wt[c * DD + k] = f2b(W[k * DD + c]);
    } else {
        int b = (bid - 64) * 256 + threadIdx.x;
        if (b < nbuck) cur[b] = b * CAP;
    }
}

// ---- FUSED A: binA role (blocks 0..nbinA-1) + gemm role (rest) ----
// binA: R1-verbatim coarse binning. gemm: raw hs = bf16(x@W), rows
// [0, ngA*256). gemm depends only on Wt, so it backfills binA's CUs
// (LDS-atomic-bound vs BW/MFMA-bound).
__global__ __launch_bounds__(256) void k_fA(const int* __restrict__ src,
                                            const int* __restrict__ dst, int E,
                                            int chunk, int nbuck,
                                            int* __restrict__ cur,
                                            int* __restrict__ binned,
                                            const float* __restrict__ x,
                                            const unsigned short* __restrict__ Wt,
                                            unsigned short* __restrict__ hs,
                                            int n, int nbinA) {
    const int t = threadIdx.x;
    if ((int)blockIdx.x < nbinA) {
        __shared__ int hist[256];
        __shared__ int base[256];
        __shared__ int curs[256];
        const int e0 = blockIdx.x * chunk;
        const int e1 = min(e0 + chunk, E);

        if (t < 256) { hist[t] = 0; curs[t] = 0; }
        __syncthreads();
        for (int e = e0 + t; e < e1; e += 256)
            atomicAdd(&hist[dst[e] >> 9], 1);
        __syncthreads();
        if (t < nbuck && hist[t] > 0)
            base[t] = atomicAdd(&cur[t], hist[t]);
        __syncthreads();
        for (int e = e0 + t; e < e1; e += 256) {
            int d = dst[e];
            int b = d >> 9;
            int p = atomicAdd(&curs[b], 1);
            int idx = base[b] + p;
            if (idx < (b + 1) * CAP)                 // statistical overflow guard
                binned[idx] = (src[e] << 9) | (d & 511);
        }
        return;
    }

    // ================= gemm role (raw, no dinv) =================
    const int wave = t >> 6, lane = t & 63;
    const int rowbase = (blockIdx.x - nbinA) * 256 + wave * 64;
    const int l15 = lane & 15, l4 = lane >> 4;

    bf16x8 a[4][4];
    #pragma unroll
    for (int rb = 0; rb < 4; ++rb) {
        int r = rowbase + rb * 16 + l15;
        int rc = min(r, n - 1);
        const float* xr = x + (size_t)rc * DD;
        #pragma unroll
        for (int kc = 0; kc < 4; ++kc) {
            int k0 = kc * 32 + l4 * 8;
            float4 f0 = *(const float4*)(xr + k0);
            float4 f1 = *(const float4*)(xr + k0 + 4);
            bf16x8 fr;
            fr[0] = (short)f2b(f0.x); fr[1] = (short)f2b(f0.y);
            fr[2] = (short)f2b(f0.z); fr[3] = (short)f2b(f0.w);
            fr[4] = (short)f2b(f1.x); fr[5] = (short)f2b(f1.y);
            fr[6] = (short)f2b(f1.z); fr[7] = (short)f2b(f1.w);
            a[rb][kc] = fr;
        }
    }

    #pragma unroll
    for (int cb = 0; cb < 8; ++cb) {
        int c0 = cb * 16;
        f32x4 acc[4] = {};
        #pragma unroll
        for (int kc = 0; kc < 4; ++kc) {
            bf16x8 bfrag = *(const bf16x8*)(Wt + (size_t)(c0 + l15) * DD + kc * 32 + l4 * 8);
            #pragma unroll
            for (int rb = 0; rb < 4; ++rb)
                acc[rb] = __builtin_amdgcn_mfma_f32_16x16x32_bf16(a[rb][kc], bfrag, acc[rb], 0, 0, 0);
        }
        #pragma unroll
        for (int rb = 0; rb < 4; ++rb) {
            int r0 = rowbase + rb * 16 + l4 * 4;
            #pragma unroll
            for (int vv = 0; vv < 4; ++vv) {
                int r = r0 + vv;
                if (r < n)
                    hs[(size_t)r * DD + c0 + l15] = f2b(acc[rb][vv]);
            }
        }
    }
}

// ---- FUSED B: binB role (blocks 0..nbuck-1) + gemm role (rest) ----
// binB: R1-verbatim per-bucket LDS counting sort. gemm: raw hs rows
// [growoff, n) at 512 thr / 256 rows per block (R4-fuse body verbatim).
__global__ __launch_bounds__(512) void k_fB(int* __restrict__ binned,
                                            const int* __restrict__ cur,
                                            int* __restrict__ off,
                                            int* __restrict__ cnt,
                                            float* __restrict__ dinv,
                                            const float* __restrict__ x,
                                            const unsigned short* __restrict__ Wt,
                                            unsigned short* __restrict__ hs,
                                            int n, int nbuck, int growoff) {
    __shared__ int hist[512];
    __shared__ int curs[512];
    __shared__ int sorted[CAP];
    const int t = threadIdx.x;

    if (blockIdx.x < (unsigned)nbuck) {
        const int b = blockIdx.x;
        const int base = b * CAP;
        const int cb = cur[b] - base;        // edges in this bucket

        hist[t] = 0;
        __syncthreads();
        for (int i = t; i < cb; i += 512)
            atomicAdd(&hist[binned[base + i] & 511], 1);
        __syncthreads();
        int v = hist[t];
        for (int st = 1; st < 512; st <<= 1) {
            int tv = (t >= st) ? hist[t - st] : 0;
            __syncthreads();
            hist[t] += tv;
            __syncthreads();
        }
        int excl = hist[t] - v;
        curs[t] = excl;
        int d = b * 512 + t;
        if (d < n) {
            off[d]  = base + excl;
            cnt[d]  = v;
            dinv[d] = rsqrtf((float)v + 1.0f);
        }
        __syncthreads();
        for (int i = t; i < cb; i += 512) {
            int pk = binned[base + i];
            int p = atomicAdd(&curs[pk & 511], 1);
            sorted[p] = pk >> 9;
        }
        __syncthreads();
        for (int i = t; i < cb; i += 512)
            binned[base + i] = sorted[i];
        return;
    }

    // ================= gemm role (raw, no dinv) =================
    const int gb = blockIdx.x - nbuck;
    const int wave = t >> 6, lane = t & 63;
    const int rowbase = growoff + gb * 256 + wave * 32;
    const int l15 = lane & 15, l4 = lane >> 4;

    bf16x8 a[2][4];
    #pragma unroll
    for (int rb = 0; rb < 2; ++rb) {
        int r = rowbase + rb * 16 + l15;
        int rc = min(r, n - 1);
        const float* xr = x + (size_t)rc * DD;
        #pragma unroll
        for (int kc = 0; kc < 4; ++kc) {
            int k0 = kc * 32 + l4 * 8;
            float4 f0 = *(const float4*)(xr + k0);
            float4 f1 = *(const float4*)(xr + k0 + 4);
            bf16x8 fr;
            fr[0] = (short)f2b(f0.x); fr[1] = (short)f2b(f0.y);
            fr[2] = (short)f2b(f0.z); fr[3] = (short)f2b(f0.w);
            fr[4] = (short)f2b(f1.x); fr[5] = (short)f2b(f1.y);
            fr[6] = (short)f2b(f1.z); fr[7] = (short)f2b(f1.w);
            a[rb][kc] = fr;
        }
    }

    #pragma unroll
    for (int cb8 = 0; cb8 < 8; ++cb8) {
        int c0 = cb8 * 16;
        f32x4 acc[2] = {};
        #pragma unroll
        for (int kc = 0; kc < 4; ++kc) {
            bf16x8 bfrag = *(const bf16x8*)(Wt + (size_t)(c0 + l15) * DD + kc * 32 + l4 * 8);
            #pragma unroll
            for (int rb = 0; rb < 2; ++rb)
                acc[rb] = __builtin_amdgcn_mfma_f32_16x16x32_bf16(a[rb][kc], bfrag, acc[rb], 0, 0, 0);
        }
        #pragma unroll
        for (int rb = 0; rb < 2; ++rb) {
            int r0 = rowbase + rb * 16 + l4 * 4;
            #pragma unroll
            for (int vv = 0; vv < 4; ++vv) {
                int r = r0 + vv;
                if (r < n)
                    hs[(size_t)r * DD + c0 + l15] = f2b(acc[rb][vv]);
            }
        }
    }
}

// ---- out[d] = dinv[d] * ( dinv[d]*h[d] + sum_s dinv[s]*h[s] ) + b
// R4-verbatim (measured 66.6 us): per-edge dinv fma, 6 batched row gathers.
__global__ __launch_bounds__(256, 8) void k_agg(const uint4* __restrict__ hsr,  // hs, row = 16 uint4
                                                const int* __restrict__ ssrc,
                                                const int* __restrict__ off,
                                                const int* __restrict__ cnt,
                                                const float* __restrict__ dinv,
                                                const float* __restrict__ bias,
                                                float* __restrict__ out, int n) {
    const int t = threadIdx.x;
    const int wave = t >> 6, lane = t & 63;
    const int q  = lane >> 4;      // quarter id 0..3
    const int ql = lane & 15;      // lane within quarter; covers bf16 cols [ql*8, ql*8+8)
    const int d = blockIdx.x * 4 + wave;
    if (d >= n) return;

    const int s0 = off[d];
    const int c  = cnt[d];
    const float di = dinv[d];

    float4 accA = {0.f, 0.f, 0.f, 0.f};
    float4 accB = {0.f, 0.f, 0.f, 0.f};

    // self row (independent, issues immediately)
    uint4 vself = hsr[(size_t)d * 16 + ql];

    // batch idx loads: 6 independent broadcast loads (quarter q, round r -> edge r*4+q)
    int idx[6];
    #pragma unroll
    for (int r = 0; r < 6; ++r) {
        int e = r * 4 + q;
        idx[r] = ssrc[s0 + ((e < c) ? e : 0)];   // in-bounds addr even when inactive
    }
    #pragma unroll
    for (int r = 0; r < 6; ++r) {
        int e = r * 4 + q;
        idx[r] = (e < c) ? idx[r] : d;           // inactive slots gather own row (safe)
    }

    // batch gathers: 6 row reads + 6 dinv loads all in flight simultaneously
    uint4 val[6];
    float sc[6];
    #pragma unroll
    for (int r = 0; r < 6; ++r) {
        val[r] = hsr[(size_t)idx[r] * 16 + ql];
        sc[r]  = dinv[idx[r]];
    }

    if (q == 0) bacc16f(accA, accB, vself, di);
    #pragma unroll
    for (int r = 0; r < 6; ++r) {
        int e = r * 4 + q;
        if (e < c) bacc16f(accA, accB, val[r], sc[r]);
    }

    // rare tail: c > 24 (P ~ 2% at mean degree 16)
    for (int i = 24 + q; i < c; i += 4) {
        int s = ssrc[s0 + i];
        uint4 v = hsr[(size_t)s * 16 + ql];
        bacc16f(accA, accB, v, dinv[s]);
    }

    // fold the 4 quarters (bits 4 and 5 of lane id)
    #pragma unroll
    for (int m = 16; m <= 32; m <<= 1) {
        accA.x += __shfl_xor(accA.x, m);
        accA.y += __shfl_xor(accA.y, m);
        accA.z += __shfl_xor(accA.z, m);
        accA.w += __shfl_xor(accA.w, m);
        accB.x += __shfl_xor(accB.x, m);
        accB.y += __shfl_xor(accB.y, m);
        accB.z += __shfl_xor(accB.z, m);
        accB.w += __shfl_xor(accB.w, m);
    }

    if (q == 0) {
        float4 b0 = ((const float4*)bias)[ql * 2];
        float4 b1 = ((const float4*)bias)[ql * 2 + 1];
        float4 o0, o1;
        o0.x = accA.x * di + b0.x;
        o0.y = accA.y * di + b0.y;
        o0.z = accA.z * di + b0.z;
        o0.w = accA.w * di + b0.w;
        o1.x = accB.x * di + b1.x;
        o1.y = accB.y * di + b1.y;
        o1.z = accB.z * di + b1.z;
        o1.w = accB.w * di + b1.w;
        float4* orow = (float4*)(out + (size_t)d * DD);
        orow[ql * 2]     = o0;
        orow[ql * 2 + 1] = o1;
    }
}

extern "C" void kernel_launch(void* const* d_in, const int* in_sizes, int n_in,
                              void* d_out, int out_size, void* d_ws, size_t ws_size,
                              hipStream_t stream) {
    const float* x  = (const float*)d_in[0];
    const int*   ei = (const int*)d_in[1];
    const float* W  = (const float*)d_in[2];
    const float* b  = (const float*)d_in[3];
    float* out = (float*)d_out;

    const int n = in_sizes[0] / DD;      // 100000
    const int E = in_sizes[1] / 2;       // 1600000
    const int* src = ei;
    const int* dst = ei + E;

    const int nbuck = (n + 511) >> 9;    // 196

    unsigned short* hs = (unsigned short*)d_ws;              // n*128 bf16 (25.6 MB)
    unsigned short* Wt = hs + (size_t)n * DD;                // 16384 bf16
    int*   binned = (int*)(Wt + DD * DD);                    // nbuck*CAP ints (9.6 MB)
    int*   off    = binned + (size_t)nbuck * CAP;            // n ints
    int*   cnt    = off + n;                                 // n ints
    float* dinv   = (float*)(cnt + n);                       // n floats
    int*   cur    = (int*)(dinv + n);                        // nbuck ints

    const int nblkA = 1024;
    const int chunk = (E + nblkA - 1) / nblkA;               // 1563

    // gemm rows split across the two fused launches
    const int ngA = 195;                     // rows [0, 49920)
    const int growoff = ngA * 256;           // 49920
    const int ngB = (n - growoff + 255) / 256;   // 196 blocks, rows [49920, n)

    k_pre<<<64 + (nbuck + 255) / 256, 256, 0, stream>>>(W, Wt, cur, nbuck);
    k_fA <<<nblkA + ngA, 256, 0, stream>>>(src, dst, E, chunk, nbuck, cur, binned,
                                           x, Wt, hs, n, nblkA);
    k_fB <<<nbuck + ngB, 512, 0, stream>>>(binned, cur, off, cnt, dinv,
                                           x, Wt, hs, n, nbuck, growoff);
    k_agg<<<(n + 3) / 4, 256, 0, stream>>>((const uint4*)hs, binned, off, cnt,
                                           dinv, b, out, n);
}

// Round 7
// 124.172 us; speedup vs baseline: 2.4246x; 1.0814x over previous
//
#include <hip/hip_runtime.h>

#define DD 128
#define CAP 12288          // per-bucket slot capacity (mean 8163, +45 sigma)

typedef __attribute__((ext_vector_type(8))) short bf16x8;
typedef __attribute__((ext_vector_type(4))) float f32x4;

__device__ inline unsigned short f2b(float f) {
    unsigned int u = __float_as_uint(f);
    u += 0x7fffu + ((u >> 16) & 1u);   // RNE
    return (unsigned short)(u >> 16);
}

// acc += bf16x8(v) * s
__device__ inline void bacc16f(float4& a, float4& b, uint4 v, float s) {
    a.x += __uint_as_float(v.x << 16) * s;
    a.y += __uint_as_float(v.x & 0xffff0000u) * s;
    a.z += __uint_as_float(v.y << 16) * s;
    a.w += __uint_as_float(v.y & 0xffff0000u) * s;
    b.x += __uint_as_float(v.z << 16) * s;
    b.y += __uint_as_float(v.z & 0xffff0000u) * s;
    b.z += __uint_as_float(v.w << 16) * s;
    b.w += __uint_as_float(v.w & 0xffff0000u) * s;
}

// ---- merged: W transpose->bf16 (blocks 0..63) + cursor init (block 64+) ----
__global__ __launch_bounds__(256) void k_pre(const float* __restrict__ W,
                                             unsigned short* __restrict__ Wt,
                                             int* __restrict__ cur, int nbuck) {
    int bid = blockIdx.x;
    if (bid < 64) {
        int idx = bid * 256 + threadIdx.x;
        int k = idx >> 7, c = idx & 127;
        Wt[c * DD + k] = f2b(W[k * DD + c]);
    } else {
        int b = (bid - 64) * 256 + threadIdx.x;
        if (b < nbuck) cur[b] = b * CAP;
    }
}

// ---- FUSED A: gemm role FIRST (blocks 0..ngA-1), binA role after ----
// binA: coarse binning, nblkA=256 / chunk=6250 so each block writes ~32
// consecutive packed values (128B = 2 full lines) per bucket -> ~4x less
// write amplification on the binned scatter (R6: 33MB partial-line writes).
// gemm: raw hs = bf16(x@W), rows [0, ngA*256); issued first so it
// co-schedules with binA from t=0 (R6 had it as a low-occupancy tail).
__global__ __launch_bounds__(256) void k_fA(const int* __restrict__ src,
                                            const int* __restrict__ dst, int E,
                                            int chunk, int nbuck,
                                            int* __restrict__ cur,
                                            int* __restrict__ binned,
                                            const float* __restrict__ x,
                                            const unsigned short* __restrict__ Wt,
                                            unsigned short* __restrict__ hs,
                                            int n, int ngA) {
    const int t = threadIdx.x;
    if ((int)blockIdx.x >= ngA) {
        __shared__ int hist[256];
        __shared__ int base[256];
        __shared__ int curs[256];
        const int e0 = (blockIdx.x - ngA) * chunk;
        const int e1 = min(e0 + chunk, E);

        if (t < 256) { hist[t] = 0; curs[t] = 0; }
        __syncthreads();
        for (int e = e0 + t; e < e1; e += 256)
            atomicAdd(&hist[dst[e] >> 9], 1);
        __syncthreads();
        if (t < nbuck && hist[t] > 0)
            base[t] = atomicAdd(&cur[t], hist[t]);
        __syncthreads();
        for (int e = e0 + t; e < e1; e += 256) {
            int d = dst[e];
            int b = d >> 9;
            int p = atomicAdd(&curs[b], 1);
            int idx = base[b] + p;
            if (idx < (b + 1) * CAP)                 // statistical overflow guard
                binned[idx] = (src[e] << 9) | (d & 511);
        }
        return;
    }

    // ================= gemm role (raw, no dinv) =================
    const int wave = t >> 6, lane = t & 63;
    const int rowbase = blockIdx.x * 256 + wave * 64;
    const int l15 = lane & 15, l4 = lane >> 4;

    bf16x8 a[4][4];
    #pragma unroll
    for (int rb = 0; rb < 4; ++rb) {
        int r = rowbase + rb * 16 + l15;
        int rc = min(r, n - 1);
        const float* xr = x + (size_t)rc * DD;
        #pragma unroll
        for (int kc = 0; kc < 4; ++kc) {
            int k0 = kc * 32 + l4 * 8;
            float4 f0 = *(const float4*)(xr + k0);
            float4 f1 = *(const float4*)(xr + k0 + 4);
            bf16x8 fr;
            fr[0] = (short)f2b(f0.x); fr[1] = (short)f2b(f0.y);
            fr[2] = (short)f2b(f0.z); fr[3] = (short)f2b(f0.w);
            fr[4] = (short)f2b(f1.x); fr[5] = (short)f2b(f1.y);
            fr[6] = (short)f2b(f1.z); fr[7] = (short)f2b(f1.w);
            a[rb][kc] = fr;
        }
    }

    #pragma unroll
    for (int cb = 0; cb < 8; ++cb) {
        int c0 = cb * 16;
        f32x4 acc[4] = {};
        #pragma unroll
        for (int kc = 0; kc < 4; ++kc) {
            bf16x8 bfrag = *(const bf16x8*)(Wt + (size_t)(c0 + l15) * DD + kc * 32 + l4 * 8);
            #pragma unroll
            for (int rb = 0; rb < 4; ++rb)
                acc[rb] = __builtin_amdgcn_mfma_f32_16x16x32_bf16(a[rb][kc], bfrag, acc[rb], 0, 0, 0);
        }
        #pragma unroll
        for (int rb = 0; rb < 4; ++rb) {
            int r0 = rowbase + rb * 16 + l4 * 4;
            #pragma unroll
            for (int vv = 0; vv < 4; ++vv) {
                int r = r0 + vv;
                if (r < n)
                    hs[(size_t)r * DD + c0 + l15] = f2b(acc[rb][vv]);
            }
        }
    }
}

// ---- FUSED B: binB role (blocks 0..nbuck-1) + gemm role (rest) ----
// R6-verbatim.
__global__ __launch_bounds__(512) void k_fB(int* __restrict__ binned,
                                            const int* __restrict__ cur,
                                            int* __restrict__ off,
                                            int* __restrict__ cnt,
                                            float* __restrict__ dinv,
                                            const float* __restrict__ x,
                                            const unsigned short* __restrict__ Wt,
                                            unsigned short* __restrict__ hs,
                                            int n, int nbuck, int growoff) {
    __shared__ int hist[512];
    __shared__ int curs[512];
    __shared__ int sorted[CAP];
    const int t = threadIdx.x;

    if (blockIdx.x < (unsigned)nbuck) {
        const int b = blockIdx.x;
        const int base = b * CAP;
        const int cb = cur[b] - base;        // edges in this bucket

        hist[t] = 0;
        __syncthreads();
        for (int i = t; i < cb; i += 512)
            atomicAdd(&hist[binned[base + i] & 511], 1);
        __syncthreads();
        int v = hist[t];
        for (int st = 1; st < 512; st <<= 1) {
            int tv = (t >= st) ? hist[t - st] : 0;
            __syncthreads();
            hist[t] += tv;
            __syncthreads();
        }
        int excl = hist[t] - v;
        curs[t] = excl;
        int d = b * 512 + t;
        if (d < n) {
            off[d]  = base + excl;
            cnt[d]  = v;
            dinv[d] = rsqrtf((float)v + 1.0f);
        }
        __syncthreads();
        for (int i = t; i < cb; i += 512) {
            int pk = binned[base + i];
            int p = atomicAdd(&curs[pk & 511], 1);
            sorted[p] = pk >> 9;
        }
        __syncthreads();
        for (int i = t; i < cb; i += 512)
            binned[base + i] = sorted[i];
        return;
    }

    // ================= gemm role (raw, no dinv) =================
    const int gb = blockIdx.x - nbuck;
    const int wave = t >> 6, lane = t & 63;
    const int rowbase = growoff + gb * 256 + wave * 32;
    const int l15 = lane & 15, l4 = lane >> 4;

    bf16x8 a[2][4];
    #pragma unroll
    for (int rb = 0; rb < 2; ++rb) {
        int r = rowbase + rb * 16 + l15;
        int rc = min(r, n - 1);
        const float* xr = x + (size_t)rc * DD;
        #pragma unroll
        for (int kc = 0; kc < 4; ++kc) {
            int k0 = kc * 32 + l4 * 8;
            float4 f0 = *(const float4*)(xr + k0);
            float4 f1 = *(const float4*)(xr + k0 + 4);
            bf16x8 fr;
            fr[0] = (short)f2b(f0.x); fr[1] = (short)f2b(f0.y);
            fr[2] = (short)f2b(f0.z); fr[3] = (short)f2b(f0.w);
            fr[4] = (short)f2b(f1.x); fr[5] = (short)f2b(f1.y);
            fr[6] = (short)f2b(f1.z); fr[7] = (short)f2b(f1.w);
            a[rb][kc] = fr;
        }
    }

    #pragma unroll
    for (int cb8 = 0; cb8 < 8; ++cb8) {
        int c0 = cb8 * 16;
        f32x4 acc[2] = {};
        #pragma unroll
        for (int kc = 0; kc < 4; ++kc) {
            bf16x8 bfrag = *(const bf16x8*)(Wt + (size_t)(c0 + l15) * DD + kc * 32 + l4 * 8);
            #pragma unroll
            for (int rb = 0; rb < 2; ++rb)
                acc[rb] = __builtin_amdgcn_mfma_f32_16x16x32_bf16(a[rb][kc], bfrag, acc[rb], 0, 0, 0);
        }
        #pragma unroll
        for (int rb = 0; rb < 2; ++rb) {
            int r0 = rowbase + rb * 16 + l4 * 4;
            #pragma unroll
            for (int vv = 0; vv < 4; ++vv) {
                int r = r0 + vv;
                if (r < n)
                    hs[(size_t)r * DD + c0 + l15] = f2b(acc[rb][vv]);
            }
        }
    }
}

// ---- out[d] = dinv[d] * ( dinv[d]*h[d] + sum_s dinv[s]*h[s] ) + b
// R4-verbatim (measured 66.6 us): per-edge dinv fma, 6 batched row gathers.
__global__ __launch_bounds__(256, 8) void k_agg(const uint4* __restrict__ hsr,  // hs, row = 16 uint4
                                                const int* __restrict__ ssrc,
                                                const int* __restrict__ off,
                                                const int* __restrict__ cnt,
                                                const float* __restrict__ dinv,
                                                const float* __restrict__ bias,
                                                float* __restrict__ out, int n) {
    const int t = threadIdx.x;
    const int wave = t >> 6, lane = t & 63;
    const int q  = lane >> 4;      // quarter id 0..3
    const int ql = lane & 15;      // lane within quarter; covers bf16 cols [ql*8, ql*8+8)
    const int d = blockIdx.x * 4 + wave;
    if (d >= n) return;

    const int s0 = off[d];
    const int c  = cnt[d];
    const float di = dinv[d];

    float4 accA = {0.f, 0.f, 0.f, 0.f};
    float4 accB = {0.f, 0.f, 0.f, 0.f};

    // self row (independent, issues immediately)
    uint4 vself = hsr[(size_t)d * 16 + ql];

    // batch idx loads: 6 independent broadcast loads (quarter q, round r -> edge r*4+q)
    int idx[6];
    #pragma unroll
    for (int r = 0; r < 6; ++r) {
        int e = r * 4 + q;
        idx[r] = ssrc[s0 + ((e < c) ? e : 0)];   // in-bounds addr even when inactive
    }
    #pragma unroll
    for (int r = 0; r < 6; ++r) {
        int e = r * 4 + q;
        idx[r] = (e < c) ? idx[r] : d;           // inactive slots gather own row (safe)
    }

    // batch gathers: 6 row reads + 6 dinv loads all in flight simultaneously
    uint4 val[6];
    float sc[6];
    #pragma unroll
    for (int r = 0; r < 6; ++r) {
        val[r] = hsr[(size_t)idx[r] * 16 + ql];
        sc[r]  = dinv[idx[r]];
    }

    if (q == 0) bacc16f(accA, accB, vself, di);
    #pragma unroll
    for (int r = 0; r < 6; ++r) {
        int e = r * 4 + q;
        if (e < c) bacc16f(accA, accB, val[r], sc[r]);
    }

    // rare tail: c > 24 (P ~ 2% at mean degree 16)
    for (int i = 24 + q; i < c; i += 4) {
        int s = ssrc[s0 + i];
        uint4 v = hsr[(size_t)s * 16 + ql];
        bacc16f(accA, accB, v, dinv[s]);
    }

    // fold the 4 quarters (bits 4 and 5 of lane id)
    #pragma unroll
    for (int m = 16; m <= 32; m <<= 1) {
        accA.x += __shfl_xor(accA.x, m);
        accA.y += __shfl_xor(accA.y, m);
        accA.z += __shfl_xor(accA.z, m);
        accA.w += __shfl_xor(accA.w, m);
        accB.x += __shfl_xor(accB.x, m);
        accB.y += __shfl_xor(accB.y, m);
        accB.z += __shfl_xor(accB.z, m);
        accB.w += __shfl_xor(accB.w, m);
    }

    if (q == 0) {
        float4 b0 = ((const float4*)bias)[ql * 2];
        float4 b1 = ((const float4*)bias)[ql * 2 + 1];
        float4 o0, o1;
        o0.x = accA.x * di + b0.x;
        o0.y = accA.y * di + b0.y;
        o0.z = accA.z * di + b0.z;
        o0.w = accA.w * di + b0.w;
        o1.x = accB.x * di + b1.x;
        o1.y = accB.y * di + b1.y;
        o1.z = accB.z * di + b1.z;
        o1.w = accB.w * di + b1.w;
        float4* orow = (float4*)(out + (size_t)d * DD);
        orow[ql * 2]     = o0;
        orow[ql * 2 + 1] = o1;
    }
}

extern "C" void kernel_launch(void* const* d_in, const int* in_sizes, int n_in,
                              void* d_out, int out_size, void* d_ws, size_t ws_size,
                              hipStream_t stream) {
    const float* x  = (const float*)d_in[0];
    const int*   ei = (const int*)d_in[1];
    const float* W  = (const float*)d_in[2];
    const float* b  = (const float*)d_in[3];
    float* out = (float*)d_out;

    const int n = in_sizes[0] / DD;      // 100000
    const int E = in_sizes[1] / 2;       // 1600000
    const int* src = ei;
    const int* dst = ei + E;

    const int nbuck = (n + 511) >> 9;    // 196

    unsigned short* hs = (unsigned short*)d_ws;              // n*128 bf16 (25.6 MB)
    unsigned short* Wt = hs + (size_t)n * DD;                // 16384 bf16
    int*   binned = (int*)(Wt + DD * DD);                    // nbuck*CAP ints (9.6 MB)
    int*   off    = binned + (size_t)nbuck * CAP;            // n ints
    int*   cnt    = off + n;                                 // n ints
    float* dinv   = (float*)(cnt + n);                       // n floats
    int*   cur    = (int*)(dinv + n);                        // nbuck ints

    const int nblkA = 256;
    const int chunk = (E + nblkA - 1) / nblkA;               // 6250

    // gemm rows split across the two fused launches
    const int ngA = 195;                     // rows [0, 49920)
    const int growoff = ngA * 256;           // 49920
    const int ngB = (n - growoff + 255) / 256;   // 196 blocks, rows [49920, n)

    k_pre<<<64 + (nbuck + 255) / 256, 256, 0, stream>>>(W, Wt, cur, nbuck);
    k_fA <<<ngA + nblkA, 256, 0, stream>>>(src, dst, E, chunk, nbuck, cur, binned,
                                           x, Wt, hs, n, ngA);
    k_fB <<<nbuck + ngB, 512, 0, stream>>>(binned, cur, off, cnt, dinv,
                                           x, Wt, hs, n, nbuck, growoff);
    k_agg<<<(n + 3) / 4, 256, 0, stream>>>((const uint4*)hs, binned, off, cnt,
                                           dinv, b, out, n);
}